// Round 7
// baseline (280.068 us; speedup 1.0000x reference)
//
#include <hip/hip_runtime.h>
#include <stdint.h>

// Top-K (K=64) per row of [4096, 32768] f32, relu'd, scattered into zeros.
//
// Round-7: split into TWO PURE STREAMS (R6 post-mortem: fused read+write
// stream caps at ~4.3 TB/s; each pure stream does ~6.3-6.6 TB/s here).
//  - Kernel F: custom zero-fill of d_out. 2048 blocks x 256 thr, grid-stride
//    nontemporal float4 stores. Pure write stream (rocclr's fill config was
//    the R5 regression, not the split idea).
//  - Kernel S: READ-ONLY select. Per float4: 3 v_max + 1 cmp + 1 branch
//    (~9% taken); candidates (>= 2.0f, ~745/row for N(0,1)) append to an LDS
//    list with a plain per-lane atomicAdd. Exact 4x8-bit radix select over
//    the candidates, ties at the exact 32-bit value included
//    lowest-index-first (matches jax.lax.top_k). Sparse scatter of <=64
//    winners per row (fill already completed in stream order -> no race).
//  - Fallback (M < 64 or M > CAP; statistically never for N(0,1)): exact
//    32-bit radix select over global re-reads, ordered tie-break, explicit
//    relu. Exactness for ANY input.

#define LROW   32768
#define NT     256
#define NWAVE  (NT / 64)            // 4
#define ITERS  (LROW / (NT * 4))    // 32
#define KSEL   64u
#define CAP    2048u
#define FCUT   2.0f                 // candidate threshold (value space)

#define FILL_BLOCKS 2048
#define FILL_NT     256

typedef float vf4 __attribute__((ext_vector_type(4)));

// float bits -> order-preserving uint (used only in the fallback)
__device__ __forceinline__ uint32_t f2o(uint32_t b) {
    return b ^ (uint32_t)(((int32_t)b >> 31) | 0x80000000u);
}
__device__ __forceinline__ float o2f(uint32_t u) {
    uint32_t b = (u & 0x80000000u) ? (u ^ 0x80000000u) : ~u;
    return __uint_as_float(b);
}

// ---- Kernel F: pure write stream ----
__global__ __launch_bounds__(FILL_NT, 8) void fill_kernel(float* __restrict__ out,
                                                          int n4)   // #float4s
{
    const vf4 z = (vf4)(0.0f);
    vf4* __restrict__ o4 = (vf4*)out;
    int stride = FILL_BLOCKS * FILL_NT;
    for (int i = blockIdx.x * FILL_NT + threadIdx.x; i < n4; i += stride)
        __builtin_nontemporal_store(z, &o4[i]);
}

// Wave 0 scans hist[nb-1..0] from the top; finds bucket b* with
// cum_before < need <= cum_before + hist[b*]; writes {b*, cum_before, hist[b*]}
// to ctrl[0..2]. Caller syncs before (hist ready) and after (result visible).
__device__ __forceinline__ void wave0_select(uint32_t* ctrl, const uint32_t* hist,
                                             int nb, uint32_t need,
                                             int tid, int lane)
{
    if (tid < 64) {
        uint32_t cum = 0;
        int done = 0;
        for (int base = nb; base > 0 && !done; base -= 64) {
            uint32_t c = hist[base - 1 - lane];   // lane 0 = highest bucket
            uint32_t inc = c;
            #pragma unroll
            for (int off = 1; off < 64; off <<= 1) {
                uint32_t t = __shfl_up(inc, off);
                if (lane >= off) inc += t;
            }
            uint32_t tot = __shfl(inc, 63);
            uint32_t pre = inc - c;
            bool hit = (cum + pre < need) && (cum + pre + c >= need);
            if (hit) {
                ctrl[0] = (uint32_t)(base - 1 - lane);
                ctrl[1] = cum + pre;
                ctrl[2] = c;
            }
            done = (__ballot(hit) != 0ull);
            cum += tot;
        }
    }
}

__device__ __forceinline__ void detect4(const float4& v, int p4,
                                        uint32_t* cu, uint32_t* cp,
                                        uint32_t* ctrl)
{
    float m = fmaxf(fmaxf(v.x, v.y), fmaxf(v.z, v.w));
    if (m >= FCUT) {                 // ~9% of lanes
        float f[4] = {v.x, v.y, v.z, v.w};
        #pragma unroll
        for (int q = 0; q < 4; ++q) {
            if (f[q] >= FCUT) {
                uint32_t idx = atomicAdd(&ctrl[3], 1u);
                if (idx < CAP) {
                    cu[idx] = __float_as_uint(f[q]);  // positive: bits ordered
                    cp[idx] = (uint32_t)(p4 * 4 + q);
                }
            }
        }
    }
}

// ---- Kernel S: pure read stream + select + sparse scatter ----
__global__ __launch_bounds__(NT, 8) void topk_kernel(
    const float* __restrict__ x, float* __restrict__ out)
{
    __shared__ uint32_t cu[CAP];     // candidate keys (raw positive-float bits)
    __shared__ uint32_t cp[CAP];     // candidate positions
    __shared__ uint32_t hist[256];
    __shared__ uint32_t ctrl[64];

    const int tid  = threadIdx.x;
    const int lane = tid & 63;
    const int wid  = tid >> 6;
    const size_t rowoff = (size_t)blockIdx.x * LROW;
    const float4* __restrict__ xin = (const float4*)(x + rowoff);

    if (tid == 0) ctrl[3] = 0u;      // candidate-append counter
    __syncthreads();

    // ---- Phase 0: pure read stream + detect ----
    for (int j = 0; j < ITERS; j += 4) {
        int p0 = (j + 0) * NT + tid;
        int p1 = (j + 1) * NT + tid;
        int p2 = (j + 2) * NT + tid;
        int p3 = (j + 3) * NT + tid;
        float4 v0 = xin[p0];
        float4 v1 = xin[p1];
        float4 v2 = xin[p2];
        float4 v3 = xin[p3];
        detect4(v0, p0, cu, cp, ctrl);
        detect4(v1, p1, cu, cp, ctrl);
        detect4(v2, p2, cu, cp, ctrl);
        detect4(v3, p3, cu, cp, ctrl);
    }
    __syncthreads();
    uint32_t M = ctrl[3];

    if (M >= KSEL && M <= CAP) {
        // ---- Main path: exact 4x8-bit radix select over M candidates ----
        uint32_t need = KSEL;
        uint32_t pref = 0;
        uint32_t cnt  = 0;
        #pragma unroll
        for (int L = 3; L >= 0; --L) {
            __syncthreads();
            if (tid < 256) hist[tid] = 0u;
            __syncthreads();
            for (uint32_t i = tid; i < M; i += NT) {
                uint32_t u = cu[i];
                bool inb = (L == 3) || ((u >> ((L + 1) * 8)) == pref);
                if (inb) atomicAdd(&hist[(u >> (L * 8)) & 0xFFu], 1u);
            }
            __syncthreads();
            wave0_select(ctrl, hist, 256, need, tid, lane);
            __syncthreads();
            uint32_t d = ctrl[0], cum = ctrl[1];
            cnt = ctrl[2];
            pref = (pref << 8) | d;
            need = need - cum;        // 1..cnt
        }
        uint32_t T32 = pref;          // exact 64th-largest key (raw bits)
        uint32_t r   = need;          // #(==T32) to include, lowest index first

        // ---- Scatter winners straight from the candidate list ----
        for (uint32_t i = tid; i < M; i += NT) {
            uint32_t u = cu[i];
            if (u > T32) {
                out[rowoff + cp[i]] = __uint_as_float(u);  // >= 2.0 > 0
            } else if (u == T32) {
                bool take = (r == cnt);
                if (!take) {
                    uint32_t myp = cp[i], rank = 0;
                    for (uint32_t j2 = 0; j2 < M; ++j2)
                        rank += (cu[j2] == T32 && cp[j2] < myp);
                    take = (rank < r);
                }
                if (take) out[rowoff + cp[i]] = __uint_as_float(u);
            }
        }
        return;
    }

    // ---- Fallback: exact 32-bit radix over global re-reads (correctness
    //      insurance; statistically never taken for N(0,1) rows) ----
    uint32_t* hist2 = cu;            // 2048-entry histogram in candidate space

    // Level A: bits 31:21
    for (int i = tid; i < 2048; i += NT) hist2[i] = 0u;
    __syncthreads();
    for (int j = 0; j < ITERS; ++j) {
        float4 v = xin[j * NT + tid];
        uint32_t u[4] = { f2o(__float_as_uint(v.x)), f2o(__float_as_uint(v.y)),
                          f2o(__float_as_uint(v.z)), f2o(__float_as_uint(v.w)) };
        #pragma unroll
        for (int q = 0; q < 4; ++q) atomicAdd(&hist2[u[q] >> 21], 1u);
    }
    __syncthreads();
    wave0_select(ctrl, hist2, 2048, KSEL, tid, lane);
    __syncthreads();
    uint32_t bA = ctrl[0], cumA = ctrl[1];
    uint32_t needB = KSEL - cumA;

    // Level B: bits 20:10 within bucket bA
    __syncthreads();
    for (int i = tid; i < 2048; i += NT) hist2[i] = 0u;
    __syncthreads();
    for (int j = 0; j < ITERS; ++j) {
        float4 v = xin[j * NT + tid];
        uint32_t u[4] = { f2o(__float_as_uint(v.x)), f2o(__float_as_uint(v.y)),
                          f2o(__float_as_uint(v.z)), f2o(__float_as_uint(v.w)) };
        #pragma unroll
        for (int q = 0; q < 4; ++q)
            if ((u[q] >> 21) == bA) atomicAdd(&hist2[(u[q] >> 10) & 0x7FFu], 1u);
    }
    __syncthreads();
    wave0_select(ctrl, hist2, 2048, needB, tid, lane);
    __syncthreads();
    uint32_t bB = ctrl[0], cumB = ctrl[1];
    uint32_t P22 = (bA << 11) | bB;
    uint32_t needC = needB - cumB;

    // Level C: bits 9:0 within prefix P22
    __syncthreads();
    for (int i = tid; i < 2048; i += NT) hist2[i] = 0u;
    __syncthreads();
    for (int j = 0; j < ITERS; ++j) {
        float4 v = xin[j * NT + tid];
        uint32_t u[4] = { f2o(__float_as_uint(v.x)), f2o(__float_as_uint(v.y)),
                          f2o(__float_as_uint(v.z)), f2o(__float_as_uint(v.w)) };
        #pragma unroll
        for (int q = 0; q < 4; ++q)
            if ((u[q] >> 10) == P22) atomicAdd(&hist2[u[q] & 0x3FFu], 1u);
    }
    __syncthreads();
    wave0_select(ctrl, hist2, 1024, needC, tid, lane);
    __syncthreads();
    uint32_t bC = ctrl[0], cumC = ctrl[1];
    uint32_t T32f = (P22 << 10) | bC;
    uint32_t r2   = needC - cumC;    // #(==T32f) to include, lowest index first

    // Ordered rank of ==T32f over contiguous chunks (index order), then scatter.
    const int cbase = tid * (LROW / NT);
    uint32_t c = 0;
    for (int j = 0; j < LROW / NT; ++j)
        c += (f2o(__float_as_uint(x[rowoff + cbase + j])) == T32f);
    uint32_t inc = c;
    #pragma unroll
    for (int off = 1; off < 64; off <<= 1) {
        uint32_t t = __shfl_up(inc, off);
        if (lane >= off) inc += t;
    }
    if (lane == 63) ctrl[16 + wid] = inc;
    __syncthreads();
    if (tid < NWAVE) {
        uint32_t v = ctrl[16 + tid];
        uint32_t inc2 = v;
        #pragma unroll
        for (int off = 1; off < NWAVE; off <<= 1) {
            uint32_t t = __shfl_up(inc2, off);
            if (lane >= off) inc2 += t;
        }
        ctrl[16 + tid] = inc2 - v;   // exclusive wave base
    }
    __syncthreads();
    uint32_t rank = ctrl[16 + wid] + (inc - c);
    for (int j = 0; j < LROW / NT; ++j) {
        uint32_t u = f2o(__float_as_uint(x[rowoff + cbase + j]));
        bool take = false;
        if (u > T32f) take = true;
        else if (u == T32f) { take = (rank < r2); rank++; }
        if (take) {
            float v = o2f(u);
            if (v > 0.f) out[rowoff + cbase + j] = v;   // relu; 0 == background
        }
    }
}

extern "C" void kernel_launch(void* const* d_in, const int* in_sizes, int n_in,
                              void* d_out, int out_size, void* d_ws, size_t ws_size,
                              hipStream_t stream)
{
    const float* x = (const float*)d_in[0];
    float* out = (float*)d_out;
    int rows = in_sizes[0] / LROW;   // 4096
    int n4   = out_size / 4;         // total float4s in output

    fill_kernel<<<FILL_BLOCKS, FILL_NT, 0, stream>>>(out, n4);
    topk_kernel<<<rows, NT, 0, stream>>>(x, out);
}

// Round 8
// 223.531 us; speedup vs baseline: 1.2529x; 1.2529x over previous
//
#include <hip/hip_runtime.h>
#include <stdint.h>

// Top-K (K=64) per row of [4096, 32768] f32, relu'd, scattered into zeros.
//
// Round-8: branchless, atomic-free, wait-free hot loop.
//   R5/R7 isolated the read-side kernel at ~199 us (2.7 TB/s) -> the
//   per-element divergent branch + LDS atomicAdd-with-return (lgkmcnt wait
//   every iteration) throttled the stream, not HBM.
//  - Each thread owns 8 LDS candidate slots + 1 shared-position trash slot.
//    Per element: UNCONDITIONAL ds_write_b64 {key,pos} to slot min(c,8);
//    c += (f >= 2.6f). No branch, no atomic, no LDS read, no waitcnt in the
//    hot loop. Non-candidate writes are overwritten by the next candidate or
//    ignored (slots >= c never read). 9th+ candidate lands in the trash slot
//    -> overflow flag -> exact fallback for that row (P ~ 1e-8 per lane).
//  - Slot layout [slot][tid]: lane stride 8 B -> conflict-free b64 writes.
//  - Post-stream: shfl prefix-scan compacts per-thread slots into one list
//    (M ~ 153 at cut 2.6 for N(0,1); needs 64 <= M <= 2048), then exact
//    4x8-bit radix select; ties at the exact 32-bit key are included
//    lowest-index-first via position compare (matches jax.lax.top_k).
//  - Zero-write stays fused (NT stores): fused beat split in R5/R7.
//  - Fallback (overflow, M < 64, statistically never): exact 32-bit radix
//    select over global re-reads, ordered tie-break, explicit relu. Exact
//    for ANY input.

#define LROW   32768
#define NT     256
#define NWAVE  (NT / 64)            // 4
#define ITERS  (LROW / (NT * 4))    // 32
#define KSEL   64u
#define CAP    2048u                // max candidates (256 thr x 8 slots)
#define NSLOT  8                    // data slots per thread (+1 trash)
#define FCUT   2.6f                 // candidate threshold (value space)

typedef float vf4 __attribute__((ext_vector_type(4)));

// float bits -> order-preserving uint (used only in the fallback)
__device__ __forceinline__ uint32_t f2o(uint32_t b) {
    return b ^ (uint32_t)(((int32_t)b >> 31) | 0x80000000u);
}
__device__ __forceinline__ float o2f(uint32_t u) {
    uint32_t b = (u & 0x80000000u) ? (u ^ 0x80000000u) : ~u;
    return __uint_as_float(b);
}

// Wave 0 scans hist[nb-1..0] from the top; finds bucket b* with
// cum_before < need <= cum_before + hist[b*]; writes {b*, cum_before, hist[b*]}
// to ctrl[0..2]. Caller syncs before (hist ready) and after (result visible).
__device__ __forceinline__ void wave0_select(uint32_t* ctrl, const uint32_t* hist,
                                             int nb, uint32_t need,
                                             int tid, int lane)
{
    if (tid < 64) {
        uint32_t cum = 0;
        int done = 0;
        for (int base = nb; base > 0 && !done; base -= 64) {
            uint32_t c = hist[base - 1 - lane];   // lane 0 = highest bucket
            uint32_t inc = c;
            #pragma unroll
            for (int off = 1; off < 64; off <<= 1) {
                uint32_t t = __shfl_up(inc, off);
                if (lane >= off) inc += t;
            }
            uint32_t tot = __shfl(inc, 63);
            uint32_t pre = inc - c;
            bool hit = (cum + pre < need) && (cum + pre + c >= need);
            if (hit) {
                ctrl[0] = (uint32_t)(base - 1 - lane);
                ctrl[1] = cum + pre;
                ctrl[2] = c;
            }
            done = (__ballot(hit) != 0ull);
            cum += tot;
        }
    }
}

// Branchless per-float4 candidate capture: unconditional slot write + cndmask
// count bump. No atomics, no branches, nothing to wait on.
__device__ __forceinline__ void scan4(const float4& v, int p4, int tid,
                                      uint2* pool, uint32_t& c)
{
    const float f0 = v.x, f1 = v.y, f2 = v.z, f3 = v.w;
    uint32_t s;
    s = (c > (uint32_t)NSLOT) ? (uint32_t)NSLOT : c;
    pool[s * NT + tid] = make_uint2(__float_as_uint(f0), (uint32_t)(p4 * 4 + 0));
    c += (f0 >= FCUT) ? 1u : 0u;
    s = (c > (uint32_t)NSLOT) ? (uint32_t)NSLOT : c;
    pool[s * NT + tid] = make_uint2(__float_as_uint(f1), (uint32_t)(p4 * 4 + 1));
    c += (f1 >= FCUT) ? 1u : 0u;
    s = (c > (uint32_t)NSLOT) ? (uint32_t)NSLOT : c;
    pool[s * NT + tid] = make_uint2(__float_as_uint(f2), (uint32_t)(p4 * 4 + 2));
    c += (f2 >= FCUT) ? 1u : 0u;
    s = (c > (uint32_t)NSLOT) ? (uint32_t)NSLOT : c;
    pool[s * NT + tid] = make_uint2(__float_as_uint(f3), (uint32_t)(p4 * 4 + 3));
    c += (f3 >= FCUT) ? 1u : 0u;
}

__global__ __launch_bounds__(NT, 8) void topk_kernel(
    const float* __restrict__ x, float* __restrict__ out)
{
    // pool: slots view [NSLOT+1][NT] during stream; list view [CAP] after.
    __shared__ uint2    pool[(NSLOT + 1) * NT];   // 18 KiB
    __shared__ uint32_t hist[256];
    __shared__ uint32_t ctrl[64];   // [0..2] select, [8] ovf, [9] M, [16..19] wave sums

    const int tid  = threadIdx.x;
    const int lane = tid & 63;
    const int wid  = tid >> 6;
    const size_t rowoff = (size_t)blockIdx.x * LROW;
    const float4* __restrict__ xin  = (const float4*)(x + rowoff);
    vf4*          __restrict__ xout = (vf4*)(out + rowoff);

    if (tid == 0) { ctrl[8] = 0u; }
    __syncthreads();

    // ---- Phase 0: fused stream: 4 loads | 4 NT zero-stores | branchless scan ----
    uint32_t c = 0;
    const vf4 z = (vf4)(0.0f);
    for (int j = 0; j < ITERS; j += 4) {
        int p0 = (j + 0) * NT + tid;
        int p1 = (j + 1) * NT + tid;
        int p2 = (j + 2) * NT + tid;
        int p3 = (j + 3) * NT + tid;
        float4 v0 = xin[p0];
        float4 v1 = xin[p1];
        float4 v2 = xin[p2];
        float4 v3 = xin[p3];
        __builtin_nontemporal_store(z, &xout[p0]);
        __builtin_nontemporal_store(z, &xout[p1]);
        __builtin_nontemporal_store(z, &xout[p2]);
        __builtin_nontemporal_store(z, &xout[p3]);
        scan4(v0, p0, tid, pool, c);
        scan4(v1, p1, tid, pool, c);
        scan4(v2, p2, tid, pool, c);
        scan4(v3, p3, tid, pool, c);
    }

    // ---- Compact per-thread slots into one candidate list ----
    uint32_t cc = (c > (uint32_t)NSLOT) ? (uint32_t)NSLOT : c;   // valid slots
    // read own slots (only this thread ever wrote them)
    uint2 mine[NSLOT];
    #pragma unroll
    for (int s = 0; s < NSLOT; ++s) mine[s] = pool[s * NT + tid];

    // prefix-scan of cc across the block
    uint32_t inc = cc;
    #pragma unroll
    for (int off = 1; off < 64; off <<= 1) {
        uint32_t t = __shfl_up(inc, off);
        if (lane >= off) inc += t;
    }
    if (lane == 63) ctrl[16 + wid] = inc;
    if (__any(c > (uint32_t)NSLOT)) ctrl[8] = 1u;   // trash slot used -> fallback
    __syncthreads();
    if (tid < NWAVE) {
        uint32_t v = ctrl[16 + tid];
        uint32_t i2 = v;
        #pragma unroll
        for (int off = 1; off < NWAVE; off <<= 1) {
            uint32_t t = __shfl_up(i2, off);
            if (lane >= off) i2 += t;
        }
        if (tid == NWAVE - 1) ctrl[9] = i2;          // total M
        ctrl[16 + tid] = i2 - v;                     // exclusive wave base
    }
    __syncthreads();
    const uint32_t M   = ctrl[9];
    const bool     ovf = (ctrl[8] != 0u);
    uint32_t ofs = ctrl[16 + wid] + (inc - cc);
    #pragma unroll
    for (int s = 0; s < NSLOT; ++s)
        if ((uint32_t)s < cc) pool[ofs + s] = mine[s];
    __syncthreads();

    if (!ovf && M >= KSEL && M <= CAP) {
        // ---- Main path: exact 4x8-bit radix select over M candidates ----
        uint32_t need = KSEL;
        uint32_t pref = 0;
        uint32_t cnt  = 0;
        #pragma unroll
        for (int L = 3; L >= 0; --L) {
            __syncthreads();
            if (tid < 256) hist[tid] = 0u;
            __syncthreads();
            for (uint32_t i = tid; i < M; i += NT) {
                uint32_t u = pool[i].x;
                bool inb = (L == 3) || ((u >> ((L + 1) * 8)) == pref);
                if (inb) atomicAdd(&hist[(u >> (L * 8)) & 0xFFu], 1u);
            }
            __syncthreads();
            wave0_select(ctrl, hist, 256, need, tid, lane);
            __syncthreads();
            uint32_t d = ctrl[0], cum = ctrl[1];
            cnt = ctrl[2];
            pref = (pref << 8) | d;
            need = need - cum;        // 1..cnt
        }
        uint32_t T32 = pref;          // exact 64th-largest key (raw bits)
        uint32_t r   = need;          // #(==T32) to include, lowest index first

        // ---- Scatter winners straight from the candidate list ----
        for (uint32_t i = tid; i < M; i += NT) {
            uint32_t u = pool[i].x;
            if (u > T32) {
                out[rowoff + pool[i].y] = __uint_as_float(u);  // >= 2.6 > 0
            } else if (u == T32) {
                bool take = (r == cnt);
                if (!take) {
                    uint32_t myp = pool[i].y, rank = 0;
                    for (uint32_t j2 = 0; j2 < M; ++j2)
                        rank += (pool[j2].x == T32 && pool[j2].y < myp);
                    take = (rank < r);
                }
                if (take) out[rowoff + pool[i].y] = __uint_as_float(u);
            }
        }
        return;
    }

    // ---- Fallback: exact 32-bit radix over global re-reads (correctness
    //      insurance; statistically never taken for N(0,1) rows) ----
    uint32_t* hist2 = (uint32_t*)pool;   // 2048-entry histogram (4608 u32 avail)

    // Level A: bits 31:21
    for (int i = tid; i < 2048; i += NT) hist2[i] = 0u;
    __syncthreads();
    for (int j = 0; j < ITERS; ++j) {
        float4 v = xin[j * NT + tid];
        uint32_t u[4] = { f2o(__float_as_uint(v.x)), f2o(__float_as_uint(v.y)),
                          f2o(__float_as_uint(v.z)), f2o(__float_as_uint(v.w)) };
        #pragma unroll
        for (int q = 0; q < 4; ++q) atomicAdd(&hist2[u[q] >> 21], 1u);
    }
    __syncthreads();
    wave0_select(ctrl, hist2, 2048, KSEL, tid, lane);
    __syncthreads();
    uint32_t bA = ctrl[0], cumA = ctrl[1];
    uint32_t needB = KSEL - cumA;

    // Level B: bits 20:10 within bucket bA
    __syncthreads();
    for (int i = tid; i < 2048; i += NT) hist2[i] = 0u;
    __syncthreads();
    for (int j = 0; j < ITERS; ++j) {
        float4 v = xin[j * NT + tid];
        uint32_t u[4] = { f2o(__float_as_uint(v.x)), f2o(__float_as_uint(v.y)),
                          f2o(__float_as_uint(v.z)), f2o(__float_as_uint(v.w)) };
        #pragma unroll
        for (int q = 0; q < 4; ++q)
            if ((u[q] >> 21) == bA) atomicAdd(&hist2[(u[q] >> 10) & 0x7FFu], 1u);
    }
    __syncthreads();
    wave0_select(ctrl, hist2, 2048, needB, tid, lane);
    __syncthreads();
    uint32_t bB = ctrl[0], cumB = ctrl[1];
    uint32_t P22 = (bA << 11) | bB;
    uint32_t needC = needB - cumB;

    // Level C: bits 9:0 within prefix P22
    __syncthreads();
    for (int i = tid; i < 2048; i += NT) hist2[i] = 0u;
    __syncthreads();
    for (int j = 0; j < ITERS; ++j) {
        float4 v = xin[j * NT + tid];
        uint32_t u[4] = { f2o(__float_as_uint(v.x)), f2o(__float_as_uint(v.y)),
                          f2o(__float_as_uint(v.z)), f2o(__float_as_uint(v.w)) };
        #pragma unroll
        for (int q = 0; q < 4; ++q)
            if ((u[q] >> 10) == P22) atomicAdd(&hist2[u[q] & 0x3FFu], 1u);
    }
    __syncthreads();
    wave0_select(ctrl, hist2, 1024, needC, tid, lane);
    __syncthreads();
    uint32_t bC = ctrl[0], cumC = ctrl[1];
    uint32_t T32f = (P22 << 10) | bC;
    uint32_t r2   = needC - cumC;    // #(==T32f) to include, lowest index first

    // Ordered rank of ==T32f over contiguous chunks (index order), then scatter.
    const int cbase = tid * (LROW / NT);
    uint32_t cc2 = 0;
    for (int j = 0; j < LROW / NT; ++j)
        cc2 += (f2o(__float_as_uint(x[rowoff + cbase + j])) == T32f);
    uint32_t inc2 = cc2;
    #pragma unroll
    for (int off = 1; off < 64; off <<= 1) {
        uint32_t t = __shfl_up(inc2, off);
        if (lane >= off) inc2 += t;
    }
    if (lane == 63) ctrl[16 + wid] = inc2;
    __syncthreads();
    if (tid < NWAVE) {
        uint32_t v = ctrl[16 + tid];
        uint32_t i2 = v;
        #pragma unroll
        for (int off = 1; off < NWAVE; off <<= 1) {
            uint32_t t = __shfl_up(i2, off);
            if (lane >= off) i2 += t;
        }
        ctrl[16 + tid] = i2 - v;     // exclusive wave base
    }
    __syncthreads();
    uint32_t rank = ctrl[16 + wid] + (inc2 - cc2);
    for (int j = 0; j < LROW / NT; ++j) {
        uint32_t u = f2o(__float_as_uint(x[rowoff + cbase + j]));
        bool take = false;
        if (u > T32f) take = true;
        else if (u == T32f) { take = (rank < r2); rank++; }
        if (take) {
            float v = o2f(u);
            if (v > 0.f) out[rowoff + cbase + j] = v;   // relu; 0 == background
        }
    }
}

extern "C" void kernel_launch(void* const* d_in, const int* in_sizes, int n_in,
                              void* d_out, int out_size, void* d_ws, size_t ws_size,
                              hipStream_t stream)
{
    const float* x = (const float*)d_in[0];
    float* out = (float*)d_out;
    int rows = in_sizes[0] / LROW;   // 4096

    topk_kernel<<<rows, NT, 0, stream>>>(x, out);
}

// Round 9
// 223.227 us; speedup vs baseline: 1.2546x; 1.0014x over previous
//
#include <hip/hip_runtime.h>
#include <stdint.h>

// Top-K (K=64) per row of [4096, 32768] f32, relu'd, scattered into zeros.
//
// Round-9: float4-GRANULARITY capture; defer element resolution off the
// critical path.
//   R8 post-mortem: branchless per-element capture (4 ds_write_b64 + ~20
//   VALU per float4) got 246->223.5 us; hot-loop instruction mass is still
//   the binding constraint beyond the HBM floor (~171 us).
//  - Hot loop per float4: m = max4 (2 v_max), unconditional ds_write_b32 of
//    the GROUP INDEX p4 to slot min(c,8), c += (m >= 2.6f). ~7 VALU + 1
//    narrow LDS write. No keys, no positions, no per-element logic.
//  - Compact (~150 groups/row, off critical path): each captured group
//    re-reads its float4 from global (16B, mostly L2/L3 hit) and appends
//    every element >= FCUT as {key,pos} to an LDS list via atomicAdd.
//    Multi-candidate groups handled exactly, for free.
//  - Exact 4x8-bit radix select over the list; ties at the exact 32-bit key
//    included lowest-index-first via position rank (matches jax.lax.top_k).
//  - Zero-write stays fused (NT float4 stores; fused beat split in R5/R7).
//  - Fallback (slot overflow, list overflow, M < 64 — statistically never):
//    exact 32-bit radix select over global re-reads, ordered tie-break,
//    explicit relu. Exact for ANY input.

#define LROW   32768
#define NT     256
#define NWAVE  (NT / 64)            // 4
#define ITERS  (LROW / (NT * 4))    // 32
#define KSEL   64u
#define CAP    1024u                // expanded candidate list capacity
#define NSLOT  8                    // group slots per thread (+1 trash)
#define FCUT   2.6f                 // candidate threshold (value space)

typedef float vf4 __attribute__((ext_vector_type(4)));

// float bits -> order-preserving uint (used only in the fallback)
__device__ __forceinline__ uint32_t f2o(uint32_t b) {
    return b ^ (uint32_t)(((int32_t)b >> 31) | 0x80000000u);
}
__device__ __forceinline__ float o2f(uint32_t u) {
    uint32_t b = (u & 0x80000000u) ? (u ^ 0x80000000u) : ~u;
    return __uint_as_float(b);
}

// Wave 0 scans hist[nb-1..0] from the top; finds bucket b* with
// cum_before < need <= cum_before + hist[b*]; writes {b*, cum_before, hist[b*]}
// to ctrl[0..2]. Caller syncs before (hist ready) and after (result visible).
__device__ __forceinline__ void wave0_select(uint32_t* ctrl, const uint32_t* hist,
                                             int nb, uint32_t need,
                                             int tid, int lane)
{
    if (tid < 64) {
        uint32_t cum = 0;
        int done = 0;
        for (int base = nb; base > 0 && !done; base -= 64) {
            uint32_t c = hist[base - 1 - lane];   // lane 0 = highest bucket
            uint32_t inc = c;
            #pragma unroll
            for (int off = 1; off < 64; off <<= 1) {
                uint32_t t = __shfl_up(inc, off);
                if (lane >= off) inc += t;
            }
            uint32_t tot = __shfl(inc, 63);
            uint32_t pre = inc - c;
            bool hit = (cum + pre < need) && (cum + pre + c >= need);
            if (hit) {
                ctrl[0] = (uint32_t)(base - 1 - lane);
                ctrl[1] = cum + pre;
                ctrl[2] = c;
            }
            done = (__ballot(hit) != 0ull);
            cum += tot;
        }
    }
}

// Lean group-granularity capture: 2 v_max + cmp/add + min + addr + ds_write_b32.
__device__ __forceinline__ void scan4g(const float4& v, int p4, int tid,
                                       uint32_t* pool, uint32_t& c)
{
    float m = fmaxf(fmaxf(v.x, v.y), fmaxf(v.z, v.w));
    uint32_t s = (c > (uint32_t)NSLOT) ? (uint32_t)NSLOT : c;
    pool[s * NT + tid] = (uint32_t)p4;
    c += (m >= FCUT) ? 1u : 0u;
}

__global__ __launch_bounds__(NT, 8) void topk_kernel(
    const float* __restrict__ x, float* __restrict__ out)
{
    __shared__ uint32_t pool[(NSLOT + 1) * NT];   // 9 KiB: captured group idxs
    __shared__ uint2    list[CAP];                // 8 KiB: expanded {key,pos}
    __shared__ uint32_t hist[256];
    __shared__ uint32_t ctrl[64];   // [0..2] select, [3] list cnt, [8] ovf, [16..] wave sums

    const int tid  = threadIdx.x;
    const int lane = tid & 63;
    const int wid  = tid >> 6;
    const size_t rowoff = (size_t)blockIdx.x * LROW;
    const float4* __restrict__ xin  = (const float4*)(x + rowoff);
    vf4*          __restrict__ xout = (vf4*)(out + rowoff);

    if (tid == 0) { ctrl[3] = 0u; ctrl[8] = 0u; }
    __syncthreads();

    // ---- Phase 0: fused stream: 4 loads | 4 NT zero-stores | lean scan ----
    uint32_t c = 0;
    const vf4 z = (vf4)(0.0f);
    for (int j = 0; j < ITERS; j += 4) {
        int p0 = (j + 0) * NT + tid;
        int p1 = (j + 1) * NT + tid;
        int p2 = (j + 2) * NT + tid;
        int p3 = (j + 3) * NT + tid;
        float4 v0 = xin[p0];
        float4 v1 = xin[p1];
        float4 v2 = xin[p2];
        float4 v3 = xin[p3];
        __builtin_nontemporal_store(z, &xout[p0]);
        __builtin_nontemporal_store(z, &xout[p1]);
        __builtin_nontemporal_store(z, &xout[p2]);
        __builtin_nontemporal_store(z, &xout[p3]);
        scan4g(v0, p0, tid, pool, c);
        scan4g(v1, p1, tid, pool, c);
        scan4g(v2, p2, tid, pool, c);
        scan4g(v3, p3, tid, pool, c);
    }

    // ---- Expand captured groups into the candidate list (off critical path) ----
    uint32_t cc = (c > (uint32_t)NSLOT) ? (uint32_t)NSLOT : c;
    if (c > (uint32_t)NSLOT) ctrl[8] = 1u;        // slot overflow -> fallback
    uint32_t my[NSLOT];
    #pragma unroll
    for (int s = 0; s < NSLOT; ++s) my[s] = pool[s * NT + tid];  // own slots only

    #pragma unroll
    for (int s = 0; s < NSLOT; ++s) {
        if ((uint32_t)s < cc) {
            uint32_t p4 = my[s];
            float4 v = xin[p4];                   // 16B gather, L2/L3-hit mostly
            float fa[4] = {v.x, v.y, v.z, v.w};
            #pragma unroll
            for (int q = 0; q < 4; ++q) {
                if (fa[q] >= FCUT) {
                    uint32_t idx = atomicAdd(&ctrl[3], 1u);
                    if (idx < CAP)
                        list[idx] = make_uint2(__float_as_uint(fa[q]),
                                               p4 * 4u + (uint32_t)q);
                    else
                        ctrl[8] = 1u;             // list overflow -> fallback
                }
            }
        }
    }
    __syncthreads();
    const uint32_t M   = ctrl[3];
    const bool     ovf = (ctrl[8] != 0u);

    if (!ovf && M >= KSEL && M <= CAP) {
        // ---- Main path: exact 4x8-bit radix select over M candidates ----
        uint32_t need = KSEL;
        uint32_t pref = 0;
        uint32_t cnt  = 0;
        #pragma unroll
        for (int L = 3; L >= 0; --L) {
            __syncthreads();
            if (tid < 256) hist[tid] = 0u;
            __syncthreads();
            for (uint32_t i = tid; i < M; i += NT) {
                uint32_t u = list[i].x;
                bool inb = (L == 3) || ((u >> ((L + 1) * 8)) == pref);
                if (inb) atomicAdd(&hist[(u >> (L * 8)) & 0xFFu], 1u);
            }
            __syncthreads();
            wave0_select(ctrl, hist, 256, need, tid, lane);
            __syncthreads();
            uint32_t d = ctrl[0], cum = ctrl[1];
            cnt = ctrl[2];
            pref = (pref << 8) | d;
            need = need - cum;        // 1..cnt
        }
        uint32_t T32 = pref;          // exact 64th-largest key (raw bits)
        uint32_t r   = need;          // #(==T32) to include, lowest index first

        // ---- Scatter winners straight from the candidate list ----
        for (uint32_t i = tid; i < M; i += NT) {
            uint32_t u = list[i].x;
            if (u > T32) {
                out[rowoff + list[i].y] = __uint_as_float(u);  // >= 2.6 > 0
            } else if (u == T32) {
                bool take = (r == cnt);
                if (!take) {
                    uint32_t myp = list[i].y, rank = 0;
                    for (uint32_t j2 = 0; j2 < M; ++j2)
                        rank += (list[j2].x == T32 && list[j2].y < myp);
                    take = (rank < r);
                }
                if (take) out[rowoff + list[i].y] = __uint_as_float(u);
            }
        }
        return;
    }

    // ---- Fallback: exact 32-bit radix over global re-reads (correctness
    //      insurance; statistically never taken for N(0,1) rows) ----
    uint32_t* hist2 = (uint32_t*)list;   // 2048 u32 available

    // Level A: bits 31:21
    for (int i = tid; i < 2048; i += NT) hist2[i] = 0u;
    __syncthreads();
    for (int j = 0; j < ITERS; ++j) {
        float4 v = xin[j * NT + tid];
        uint32_t u[4] = { f2o(__float_as_uint(v.x)), f2o(__float_as_uint(v.y)),
                          f2o(__float_as_uint(v.z)), f2o(__float_as_uint(v.w)) };
        #pragma unroll
        for (int q = 0; q < 4; ++q) atomicAdd(&hist2[u[q] >> 21], 1u);
    }
    __syncthreads();
    wave0_select(ctrl, hist2, 2048, KSEL, tid, lane);
    __syncthreads();
    uint32_t bA = ctrl[0], cumA = ctrl[1];
    uint32_t needB = KSEL - cumA;

    // Level B: bits 20:10 within bucket bA
    __syncthreads();
    for (int i = tid; i < 2048; i += NT) hist2[i] = 0u;
    __syncthreads();
    for (int j = 0; j < ITERS; ++j) {
        float4 v = xin[j * NT + tid];
        uint32_t u[4] = { f2o(__float_as_uint(v.x)), f2o(__float_as_uint(v.y)),
                          f2o(__float_as_uint(v.z)), f2o(__float_as_uint(v.w)) };
        #pragma unroll
        for (int q = 0; q < 4; ++q)
            if ((u[q] >> 21) == bA) atomicAdd(&hist2[(u[q] >> 10) & 0x7FFu], 1u);
    }
    __syncthreads();
    wave0_select(ctrl, hist2, 2048, needB, tid, lane);
    __syncthreads();
    uint32_t bB = ctrl[0], cumB = ctrl[1];
    uint32_t P22 = (bA << 11) | bB;
    uint32_t needC = needB - cumB;

    // Level C: bits 9:0 within prefix P22
    __syncthreads();
    for (int i = tid; i < 2048; i += NT) hist2[i] = 0u;
    __syncthreads();
    for (int j = 0; j < ITERS; ++j) {
        float4 v = xin[j * NT + tid];
        uint32_t u[4] = { f2o(__float_as_uint(v.x)), f2o(__float_as_uint(v.y)),
                          f2o(__float_as_uint(v.z)), f2o(__float_as_uint(v.w)) };
        #pragma unroll
        for (int q = 0; q < 4; ++q)
            if ((u[q] >> 10) == P22) atomicAdd(&hist2[u[q] & 0x3FFu], 1u);
    }
    __syncthreads();
    wave0_select(ctrl, hist2, 1024, needC, tid, lane);
    __syncthreads();
    uint32_t bC = ctrl[0], cumC = ctrl[1];
    uint32_t T32f = (P22 << 10) | bC;
    uint32_t r2   = needC - cumC;    // #(==T32f) to include, lowest index first

    // Ordered rank of ==T32f over contiguous chunks (index order), then scatter.
    const int cbase = tid * (LROW / NT);
    uint32_t cc2 = 0;
    for (int j = 0; j < LROW / NT; ++j)
        cc2 += (f2o(__float_as_uint(x[rowoff + cbase + j])) == T32f);
    uint32_t inc2 = cc2;
    #pragma unroll
    for (int off = 1; off < 64; off <<= 1) {
        uint32_t t = __shfl_up(inc2, off);
        if (lane >= off) inc2 += t;
    }
    if (lane == 63) ctrl[16 + wid] = inc2;
    __syncthreads();
    if (tid < NWAVE) {
        uint32_t v = ctrl[16 + tid];
        uint32_t i2 = v;
        #pragma unroll
        for (int off = 1; off < NWAVE; off <<= 1) {
            uint32_t t = __shfl_up(i2, off);
            if (lane >= off) i2 += t;
        }
        ctrl[16 + tid] = i2 - v;     // exclusive wave base
    }
    __syncthreads();
    uint32_t rank = ctrl[16 + wid] + (inc2 - cc2);
    for (int j = 0; j < LROW / NT; ++j) {
        uint32_t u = f2o(__float_as_uint(x[rowoff + cbase + j]));
        bool take = false;
        if (u > T32f) take = true;
        else if (u == T32f) { take = (rank < r2); rank++; }
        if (take) {
            float v = o2f(u);
            if (v > 0.f) out[rowoff + cbase + j] = v;   // relu; 0 == background
        }
    }
}

extern "C" void kernel_launch(void* const* d_in, const int* in_sizes, int n_in,
                              void* d_out, int out_size, void* d_ws, size_t ws_size,
                              hipStream_t stream)
{
    const float* x = (const float*)d_in[0];
    float* out = (float*)d_out;
    int rows = in_sizes[0] / LROW;   // 4096

    topk_kernel<<<rows, NT, 0, stream>>>(x, out);
}